// Round 7
// baseline (285.206 us; speedup 1.0000x reference)
//
#include <hip/hip_runtime.h>

#define HW_   (512 * 512)   // pixels per image
#define NIMG  8
#define NC    19            // classes
#define NSP   2048          // superpixels per image
#define TC    20            // target row stride (C+1, last col sliced off)
#define NROWS (NIMG * NSP)  // 16384 target rows
#define NBLK  256           // persistent blocks: ONE per CU, single pass
#define NGRP  16            // completion-ticket groups (16 blocks each)
#define GSIZE (NBLK / NGRP)

typedef float vf4 __attribute__((ext_vector_type(4)));
typedef int   vi4 __attribute__((ext_vector_type(4)));

// d_ws layout:
//   [0]    flag (uint)       spmask width: 1 -> 4-byte, 0 -> 1-byte
//   [4]    st   (uint)       super ticket
//   [64]   gt[NGRP] uints, stride 16 (64 B apart -> no same-line RMWs)
//   [1088] pl[NBLK] float    per-block loss partials (contention-free)
//   [3136] pc[NBLK] uint     per-block count partials
//   [5184] bmt[NROWS] uint   per-(image,superpixel) multi-hot bitmask

// ---------------------------------------------------------------------------
// Kernel 1: zero tickets, detect spmask width, build target bitmasks.
// ---------------------------------------------------------------------------
__global__ __launch_bounds__(256) void prep(
    const float* __restrict__ tgt,
    const unsigned int* __restrict__ spm,
    unsigned int* __restrict__ flag, unsigned int* __restrict__ st,
    unsigned int* __restrict__ gt, unsigned int* __restrict__ bm) {

    int gid = blockIdx.x * 256 + threadIdx.x;   // 64 blocks -> 16384 threads
    if (gid == 0) *st = 0u;
    if (gid < NGRP) gt[gid * 16] = 0u;

    if (blockIdx.x == 1 && threadIdx.x < 64) {  // one wave: width detection
        unsigned int nonlow = 0, upper = 0;
        for (int i = threadIdx.x; i < 1024; i += 64) {
            unsigned int v = spm[i];
            nonlow |= (v & 0xFEFEFEFEu);
            upper  |= (v & 0xFFFFFF00u);
        }
        unsigned long long b1 = __ballot(nonlow != 0);
        unsigned long long b2 = __ballot(upper != 0);
        if (threadIdx.x == 0)
            *flag = ((b1 == 0ull) && (b2 != 0ull)) ? 0u : 1u;
    }

    const float* row = tgt + (size_t)gid * TC;  // one thread per target row
    unsigned int m = 0;
#pragma unroll
    for (int c = 0; c < NC; ++c)
        m |= (row[c] != 0.0f ? 1u : 0u) << c;
    bm[gid] = m;
}

// ---------------------------------------------------------------------------
// Kernel 2: RUN-LENGTH PROBE at the winning occupancy.
// 256 blocks (1/CU), 4 waves, SINGLE pass, class-OUTER:
//   block b -> image n = b&7 (XCD affinity under round-robin dispatch),
//   stripe s = b>>3 (32 stripes of 8192 px per image). Each wave owns a
//   contiguous 2048-px sub-stripe; per class it issues 8 back-to-back
//   dwordx4 covering 8 KB CONTIGUOUS (run length 8) before the 1-MB jump
//   to the next class plane -- vs run length 1 in all fast variants so far.
//   Discriminates "stream-switch cost is the per-CU serializer" (-> ~2x)
//   from "per-CU delivery ~3.4 B/cyc regardless of pattern" (-> neutral).
// 32 px/thread: se/ts/bv live in registers (launch_bounds(256,1) -> 512
// VGPR cap, ~200 live, no spill; WRITE_SIZE must stay ~0). bmt staged to
// LDS (8 KB), per-pixel bitmask lookups are ds_read (off the vmem pipe).
// Per-pixel FP order (ascending classes) identical to R1/R4/R6.
// ---------------------------------------------------------------------------
__global__ __launch_bounds__(256, 1) void mcce_main(
    const float* __restrict__ x,      // (N, C, H*W)
    const int*   __restrict__ sp,     // (N, H*W)
    const void*  __restrict__ spm,    // (N, H*W) mask, 1B or 4B elements
    const unsigned int* __restrict__ bmt,   // (N*NSP) bitmasks
    const unsigned int* __restrict__ flag,
    float* __restrict__ pl, unsigned int* __restrict__ pc,
    unsigned int* __restrict__ st, unsigned int* __restrict__ gt,
    float* __restrict__ out) {

    __shared__ unsigned int bmtab[NSP];  // 8 KB: this image's bitmasks
    __shared__ float sL[4];
    __shared__ unsigned int sC[4];

    int b    = blockIdx.x;
    int t    = threadIdx.x;
    int wave = t >> 6;
    int lane = t & 63;

    int n     = b & 7;                   // image (XCD affinity)
    int sbase = (b >> 3) * 8192;         // stripe base pixel within image
    int wbase = sbase + wave * 2048;     // this wave's contiguous 2048 px
    unsigned int flagv = *flag;          // wave-uniform (prep completed)

    // ---- stage this image's bitmask table into LDS (coalesced) ----
    const vi4* btv = (const vi4*)(bmt + (size_t)n * NSP);
    ((vi4*)bmtab)[t]       = btv[t];
    ((vi4*)bmtab)[t + 256] = btv[t + 256];

    // ---- sp indices: 8 KB contiguous per wave (8 dwordx4/thread) ----
    const int* spw = sp + (size_t)n * HW_ + wbase;
    vi4 s4[8];
#pragma unroll
    for (int k = 0; k < 8; ++k)
        s4[k] = ((const vi4*)spw)[lane + k * 64];

    // ---- spmask: 4-bit valid-mask per 4-px group ----
    int mkb[8];
    size_t mbase = (size_t)n * HW_ + wbase;
    if (flagv) {
#pragma unroll
        for (int k = 0; k < 8; ++k) {
            vi4 m = ((const vi4*)((const int*)spm + mbase))[lane + k * 64];
            mkb[k] = (m.x != 0 ? 1 : 0) | (m.y != 0 ? 2 : 0) |
                     (m.z != 0 ? 4 : 0) | (m.w != 0 ? 8 : 0);
        }
    } else {
#pragma unroll
        for (int k = 0; k < 8; ++k) {
            unsigned int mw = ((const unsigned int*)
                               ((const unsigned char*)spm + mbase))[lane + k * 64];
            mkb[k] = ((mw        & 0xFFu) ? 1 : 0) | (((mw >> 8)  & 0xFFu) ? 2 : 0) |
                     (((mw >> 16) & 0xFFu) ? 4 : 0) | (((mw >> 24) & 0xFFu) ? 8 : 0);
        }
    }

    __syncthreads();                     // bmtab ready

    // ---- per-pixel bitmasks from LDS (vmem pipe untouched) ----
    unsigned int bv[8][4];
#pragma unroll
    for (int k = 0; k < 8; ++k) {
        bv[k][0] = bmtab[s4[k].x]; bv[k][1] = bmtab[s4[k].y];
        bv[k][2] = bmtab[s4[k].z]; bv[k][3] = bmtab[s4[k].w];
    }

    // ---- class-outer streaming accumulation, 2-deep A/B pipeline ----
    // Per class per wave: 8 consecutive dwordx4 = 8 KB contiguous run.
    const float* xw = x + (size_t)n * NC * HW_ + wbase;   // class-0 base
    vf4 A[8], B[8];
    vf4 se[8], ts[8];
#pragma unroll
    for (int k = 0; k < 8; ++k) { se[k] = (vf4){0,0,0,0}; ts[k] = (vf4){0,0,0,0}; }

#define LDC(R, c) { const vf4* p_ = (const vf4*)(xw + (size_t)(c) * HW_);      \
    _Pragma("unroll") for (int k_ = 0; k_ < 8; ++k_) R[k_] = p_[lane + k_*64]; }

#define PRC(R, c) { _Pragma("unroll") for (int k_ = 0; k_ < 8; ++k_) {         \
    vf4 e_;                                                                    \
    e_.x = __expf(R[k_].x); e_.y = __expf(R[k_].y);                            \
    e_.z = __expf(R[k_].z); e_.w = __expf(R[k_].w);                            \
    se[k_].x += e_.x; se[k_].y += e_.y; se[k_].z += e_.z; se[k_].w += e_.w;    \
    ts[k_].x += ((bv[k_][0] >> (c)) & 1) ? e_.x : 0.0f;                        \
    ts[k_].y += ((bv[k_][1] >> (c)) & 1) ? e_.y : 0.0f;                        \
    ts[k_].z += ((bv[k_][2] >> (c)) & 1) ? e_.z : 0.0f;                        \
    ts[k_].w += ((bv[k_][3] >> (c)) & 1) ? e_.w : 0.0f; } }

    LDC(A, 0)
#pragma unroll
    for (int p = 0; p < 9; ++p) {        // classes 2p, 2p+1; preload 2p+2
        LDC(B, 2 * p + 1)
        PRC(A, 2 * p)
        LDC(A, 2 * p + 2)                // p=8 -> class 18
        PRC(B, 2 * p + 1)
    }
    PRC(A, 18)

#undef LDC
#undef PRC

    // ---- per-lane NLL over 32 pixels ----
    float lsum = 0.0f;
    unsigned int lcnt = 0;
#pragma unroll
    for (int k = 0; k < 8; ++k) {
        if ((mkb[k] & 1) && bv[k][0]) { lsum -= __logf(ts[k].x / se[k].x + 1e-8f); ++lcnt; }
        if ((mkb[k] & 2) && bv[k][1]) { lsum -= __logf(ts[k].y / se[k].y + 1e-8f); ++lcnt; }
        if ((mkb[k] & 4) && bv[k][2]) { lsum -= __logf(ts[k].z / se[k].z + 1e-8f); ++lcnt; }
        if ((mkb[k] & 8) && bv[k][3]) { lsum -= __logf(ts[k].w / se[k].w + 1e-8f); ++lcnt; }
    }

    // ---- wave-64 shuffle reduction -> LDS block reduction ----
    for (int o = 32; o > 0; o >>= 1) {
        lsum += __shfl_down(lsum, o);
        lcnt += __shfl_down(lcnt, o);
    }
    __syncthreads();                     // bmtab dead; reuse sL/sC region
    if ((t & 63) == 0) { sL[wave] = lsum; sC[wave] = lcnt; }
    __syncthreads();

    if (t == 0) {
        float        L = sL[0] + sL[1] + sL[2] + sL[3];
        unsigned int C = sC[0] + sC[1] + sC[2] + sC[3];
        __hip_atomic_store(&pl[b], L, __ATOMIC_RELAXED, __HIP_MEMORY_SCOPE_AGENT);
        __hip_atomic_store(&pc[b], C, __ATOMIC_RELAXED, __HIP_MEMORY_SCOPE_AGENT);
        // Hierarchical tickets: 16 groups of 16 (64-B-padded lines), then
        // one super ticket.
        unsigned int g = (unsigned int)b / GSIZE;
        unsigned int isLast = 0u;
        unsigned int tk = __hip_atomic_fetch_add(&gt[g * 16], 1u,
                              __ATOMIC_ACQ_REL, __HIP_MEMORY_SCOPE_AGENT);
        if (tk == (unsigned int)(GSIZE - 1)) {
            unsigned int s = __hip_atomic_fetch_add(st, 1u,
                                 __ATOMIC_ACQ_REL, __HIP_MEMORY_SCOPE_AGENT);
            isLast = (s == NGRP - 1) ? 1u : 0u;
        }
        sC[0] = isLast;                  // reuse LDS as broadcast
    }
    __syncthreads();

    // Last block: reduce the 256 partials and write the scalar.
    if (sC[0]) {
        float        L = 0.0f;
        unsigned int C = 0u;
        for (int i = t; i < NBLK; i += 256) {
            L += __hip_atomic_load(&pl[i], __ATOMIC_RELAXED, __HIP_MEMORY_SCOPE_AGENT);
            C += __hip_atomic_load(&pc[i], __ATOMIC_RELAXED, __HIP_MEMORY_SCOPE_AGENT);
        }
        for (int o = 32; o > 0; o >>= 1) {
            L += __shfl_down(L, o);
            C += __shfl_down(C, o);
        }
        __syncthreads();                 // LDS reuse barrier
        if ((t & 63) == 0) { sL[wave] = L; sC[wave] = C; }
        __syncthreads();
        if (t == 0) {
            L = sL[0] + sL[1] + sL[2] + sL[3];
            C = sC[0] + sC[1] + sC[2] + sC[3];
            out[0] = L / (float)(1u + C);
        }
    }
}

extern "C" void kernel_launch(void* const* d_in, const int* in_sizes, int n_in,
                              void* d_out, int out_size, void* d_ws, size_t ws_size,
                              hipStream_t stream) {
    const float* x   = (const float*)d_in[0];   // inputs (8,19,512,512) f32
    const float* tgt = (const float*)d_in[1];   // targets (8,2048,20) f32
    const int*   sp  = (const int*)d_in[2];     // superpixels (8,512,512) i32
    const void*  spm = d_in[3];                 // spmasks (8,512,512), width detected

    unsigned int* flag = (unsigned int*)d_ws;
    unsigned int* st   = (unsigned int*)((char*)d_ws + 4);
    unsigned int* gt   = (unsigned int*)((char*)d_ws + 64);
    float*        pl   = (float*)((char*)d_ws + 1088);
    unsigned int* pc   = (unsigned int*)((char*)d_ws + 3136);
    unsigned int* bmt  = (unsigned int*)((char*)d_ws + 5184);

    prep<<<NROWS / 256, 256, 0, stream>>>(tgt, (const unsigned int*)spm,
                                          flag, st, gt, bmt);

    mcce_main<<<NBLK, 256, 0, stream>>>(x, sp, spm, bmt, flag,
                                        pl, pc, st, gt, (float*)d_out);
}

// Round 8
// 242.248 us; speedup vs baseline: 1.1773x; 1.1773x over previous
//
#include <hip/hip_runtime.h>

#define HW_   (512 * 512)   // pixels per image
#define NIMG  8
#define NC    19            // classes
#define NSP   2048          // superpixels per image
#define TC    20            // target row stride (C+1, last col sliced off)
#define NROWS (NIMG * NSP)  // 16384 target rows
#define TILE  1024          // pixels per tile (4 per thread)
#define NTILE (NIMG * HW_ / TILE)   // 2048 tiles
#define NBLK  256           // persistent blocks: ONE per CU
#define NITER (NTILE / NBLK)        // 8 tiles per block; iter == one image
#define NGRP  16            // completion-ticket groups (16 blocks each)
#define GSIZE (NBLK / NGRP)

typedef float vf4 __attribute__((ext_vector_type(4)));
typedef int   vi4 __attribute__((ext_vector_type(4)));

// d_ws layout:
//   [0]    flag (uint)       spmask width: 1 -> 4-byte, 0 -> 1-byte
//   [4]    st   (uint)       super ticket
//   [64]   gt[NGRP] uints, stride 16 (64 B apart -> no same-line RMWs)
//   [1088] pl[NBLK] float    per-block loss partials (contention-free)
//   [3136] pc[NBLK] uint     per-block count partials
//   [5184] bmt[NROWS] uint   per-(image,superpixel) multi-hot bitmask

// ---------------------------------------------------------------------------
// Kernel 1: zero tickets, detect spmask width, build target bitmasks.
// ---------------------------------------------------------------------------
__global__ __launch_bounds__(256) void prep(
    const float* __restrict__ tgt,
    const unsigned int* __restrict__ spm,
    unsigned int* __restrict__ flag, unsigned int* __restrict__ st,
    unsigned int* __restrict__ gt, unsigned int* __restrict__ bm) {

    int gid = blockIdx.x * 256 + threadIdx.x;   // 64 blocks -> 16384 threads
    if (gid == 0) *st = 0u;
    if (gid < NGRP) gt[gid * 16] = 0u;

    if (blockIdx.x == 1 && threadIdx.x < 64) {  // one wave: width detection
        unsigned int nonlow = 0, upper = 0;
        for (int i = threadIdx.x; i < 1024; i += 64) {
            unsigned int v = spm[i];
            nonlow |= (v & 0xFEFEFEFEu);
            upper  |= (v & 0xFFFFFF00u);
        }
        unsigned long long b1 = __ballot(nonlow != 0);
        unsigned long long b2 = __ballot(upper != 0);
        if (threadIdx.x == 0)
            *flag = ((b1 == 0ull) && (b2 != 0ull)) ? 0u : 1u;
    }

    const float* row = tgt + (size_t)gid * TC;  // one thread per target row
    unsigned int m = 0;
#pragma unroll
    for (int c = 0; c < NC; ++c)
        m |= (row[c] != 0.0f ? 1u : 0u) << c;
    bm[gid] = m;
}

// ---------------------------------------------------------------------------
// Kernel 2: persistent-block, IMAGE-SERIAL fused exp-sum + gather + NLL.
// Identical to the best-measured R6 structure (1 block/CU, 8 image-serial
// iterations, 20-load dwordx4 burst, single trailing vmcnt(0)) with ONE
// change: the 19 x-loads carry the `nt` (non-temporal) hint. Every x line
// is consumed exactly once per pass; 20k concurrent read-once streams all
// ALLOCATING lines in L1/L2 on the return path is the remaining suspect
// for the structure-independent ~3.2 B/cyc/CU delivery cap (the harness's
// own fill kernel proves 6.7 TB/s fabric capability). `nt` marks the
// stream evict-first/no-allocate, taking victim/allocation machinery off
// the critical path. One variable vs R6; trivially revertible.
// ---------------------------------------------------------------------------
__global__ __launch_bounds__(256, 1) void mcce_main(
    const float* __restrict__ x,      // (N, C, H*W)
    const int*   __restrict__ sp,     // (N, H*W)
    const void*  __restrict__ spm,    // (N, H*W) mask, 1B or 4B elements
    const unsigned int* __restrict__ bmt,   // (N*NSP) bitmasks
    const unsigned int* __restrict__ flag,
    float* __restrict__ pl, unsigned int* __restrict__ pc,
    unsigned int* __restrict__ st, unsigned int* __restrict__ gt,
    float* __restrict__ out) {

    __shared__ float sL[4];
    __shared__ unsigned int sC[4];

    int b    = blockIdx.x;
    int t    = threadIdx.x;
    int wave = t >> 6;
    unsigned int flagv = *flag;        // hoisted; wave-uniform

    float lsum = 0.0f;
    unsigned int lcnt = 0;

#pragma unroll 1
    for (int it = 0; it < NITER; ++it) {
        int T  = it * NBLK + b;        // NBLK=256 -> n = it, tile b of image it
        int n  = T >> 8;               // 256 tiles per image
        int tp = (T & 255) * TILE;     // tile base pixel within image
        size_t gp = (size_t)n * HW_ + tp + 4 * t;   // this thread's 4 pixels

        const float* xb  = x  + (size_t)n * NC * HW_ + tp;
        const int*   spb = sp + (size_t)n * HW_ + tp;
        unsigned int vo  = (unsigned int)(t * 16);  // byte offset

        vf4 d0,d1,d2,d3,d4,d5,d6,d7,d8,d9,d10,d11,d12,d13,d14,d15,d16,d17,d18;
        vi4 s4;

        // 20 dwordx4 loads back-to-back, one wait. Class stride = 1 MB.
        // x-loads are non-temporal (read-once stream).
        asm volatile(
            "global_load_dwordx4 %[s4],  %[vo], %[spb]\n\t"
            "global_load_dwordx4 %[d0],  %[vo], %[xb] nt\n\t"
            "v_add_u32 %[vo], 0x100000, %[vo]\n\t"
            "global_load_dwordx4 %[d1],  %[vo], %[xb] nt\n\t"
            "v_add_u32 %[vo], 0x100000, %[vo]\n\t"
            "global_load_dwordx4 %[d2],  %[vo], %[xb] nt\n\t"
            "v_add_u32 %[vo], 0x100000, %[vo]\n\t"
            "global_load_dwordx4 %[d3],  %[vo], %[xb] nt\n\t"
            "v_add_u32 %[vo], 0x100000, %[vo]\n\t"
            "global_load_dwordx4 %[d4],  %[vo], %[xb] nt\n\t"
            "v_add_u32 %[vo], 0x100000, %[vo]\n\t"
            "global_load_dwordx4 %[d5],  %[vo], %[xb] nt\n\t"
            "v_add_u32 %[vo], 0x100000, %[vo]\n\t"
            "global_load_dwordx4 %[d6],  %[vo], %[xb] nt\n\t"
            "v_add_u32 %[vo], 0x100000, %[vo]\n\t"
            "global_load_dwordx4 %[d7],  %[vo], %[xb] nt\n\t"
            "v_add_u32 %[vo], 0x100000, %[vo]\n\t"
            "global_load_dwordx4 %[d8],  %[vo], %[xb] nt\n\t"
            "v_add_u32 %[vo], 0x100000, %[vo]\n\t"
            "global_load_dwordx4 %[d9],  %[vo], %[xb] nt\n\t"
            "v_add_u32 %[vo], 0x100000, %[vo]\n\t"
            "global_load_dwordx4 %[d10], %[vo], %[xb] nt\n\t"
            "v_add_u32 %[vo], 0x100000, %[vo]\n\t"
            "global_load_dwordx4 %[d11], %[vo], %[xb] nt\n\t"
            "v_add_u32 %[vo], 0x100000, %[vo]\n\t"
            "global_load_dwordx4 %[d12], %[vo], %[xb] nt\n\t"
            "v_add_u32 %[vo], 0x100000, %[vo]\n\t"
            "global_load_dwordx4 %[d13], %[vo], %[xb] nt\n\t"
            "v_add_u32 %[vo], 0x100000, %[vo]\n\t"
            "global_load_dwordx4 %[d14], %[vo], %[xb] nt\n\t"
            "v_add_u32 %[vo], 0x100000, %[vo]\n\t"
            "global_load_dwordx4 %[d15], %[vo], %[xb] nt\n\t"
            "v_add_u32 %[vo], 0x100000, %[vo]\n\t"
            "global_load_dwordx4 %[d16], %[vo], %[xb] nt\n\t"
            "v_add_u32 %[vo], 0x100000, %[vo]\n\t"
            "global_load_dwordx4 %[d17], %[vo], %[xb] nt\n\t"
            "v_add_u32 %[vo], 0x100000, %[vo]\n\t"
            "global_load_dwordx4 %[d18], %[vo], %[xb] nt\n\t"
            "s_waitcnt vmcnt(0)"
            : [d0]"=v"(d0), [d1]"=v"(d1), [d2]"=v"(d2), [d3]"=v"(d3),
              [d4]"=v"(d4), [d5]"=v"(d5), [d6]"=v"(d6), [d7]"=v"(d7),
              [d8]"=v"(d8), [d9]"=v"(d9), [d10]"=v"(d10), [d11]"=v"(d11),
              [d12]"=v"(d12), [d13]"=v"(d13), [d14]"=v"(d14), [d15]"=v"(d15),
              [d16]"=v"(d16), [d17]"=v"(d17), [d18]"=v"(d18),
              [s4]"=v"(s4), [vo]"+v"(vo)
            : [xb]"s"(xb), [spb]"s"(spb));

        // Mask (wave-uniform width branch) + bitmask gathers (L2-resident).
        int mk[4];
        if (flagv) {
            vi4 m = *(const vi4*)((const int*)spm + gp);
            mk[0] = m.x; mk[1] = m.y; mk[2] = m.z; mk[3] = m.w;
        } else {
            unsigned int mw = *(const unsigned int*)
                              ((const unsigned char*)spm + gp);
            mk[0] = mw & 0xFF; mk[1] = (mw >> 8) & 0xFF;
            mk[2] = (mw >> 16) & 0xFF; mk[3] = (mw >> 24) & 0xFF;
        }
        const unsigned int* bt = bmt + n * NSP;
        unsigned int bmv[4] = {bt[s4.x], bt[s4.y], bt[s4.z], bt[s4.w]};

        // Streaming exp-sums (no max-subtraction: inputs ~N(0,1), fp32-safe).
        vf4 dv[NC] = {d0,d1,d2,d3,d4,d5,d6,d7,d8,d9,
                      d10,d11,d12,d13,d14,d15,d16,d17,d18};
        float se[4] = {0,0,0,0}, ts[4] = {0,0,0,0};
#pragma unroll
        for (int c = 0; c < NC; ++c) {
            float e0 = __expf(dv[c].x), e1 = __expf(dv[c].y);
            float e2 = __expf(dv[c].z), e3 = __expf(dv[c].w);
            se[0] += e0; se[1] += e1; se[2] += e2; se[3] += e3;
            ts[0] += ((bmv[0] >> c) & 1) ? e0 : 0.0f;
            ts[1] += ((bmv[1] >> c) & 1) ? e1 : 0.0f;
            ts[2] += ((bmv[2] >> c) & 1) ? e2 : 0.0f;
            ts[3] += ((bmv[3] >> c) & 1) ? e3 : 0.0f;
        }
#pragma unroll
        for (int j = 0; j < 4; ++j) {
            if ((mk[j] != 0) && (bmv[j] != 0u)) {
                lsum -= __logf(ts[j] / se[j] + 1e-8f);
                ++lcnt;
            }
        }
    }

    // Wave-64 shuffle reduction -> LDS block reduction.
    for (int o = 32; o > 0; o >>= 1) {
        lsum += __shfl_down(lsum, o);
        lcnt += __shfl_down(lcnt, o);
    }
    if ((t & 63) == 0) { sL[wave] = lsum; sC[wave] = lcnt; }
    __syncthreads();

    if (t == 0) {
        float        L = sL[0] + sL[1] + sL[2] + sL[3];
        unsigned int C = sC[0] + sC[1] + sC[2] + sC[3];
        // Private slot per block -> zero contention; agent scope for
        // cross-XCD visibility to the finalizing block.
        __hip_atomic_store(&pl[b], L, __ATOMIC_RELAXED,
                           __HIP_MEMORY_SCOPE_AGENT);
        __hip_atomic_store(&pc[b], C, __ATOMIC_RELAXED,
                           __HIP_MEMORY_SCOPE_AGENT);
        // Hierarchical tickets: 16 groups of 16 (64-B-padded lines), then
        // one super ticket -> max ~16 same-line RMWs anywhere.
        unsigned int g = (unsigned int)b / GSIZE;
        unsigned int isLast = 0u;
        unsigned int tk = __hip_atomic_fetch_add(&gt[g * 16], 1u,
                              __ATOMIC_ACQ_REL, __HIP_MEMORY_SCOPE_AGENT);
        if (tk == (unsigned int)(GSIZE - 1)) {
            unsigned int s = __hip_atomic_fetch_add(st, 1u,
                                 __ATOMIC_ACQ_REL, __HIP_MEMORY_SCOPE_AGENT);
            isLast = (s == NGRP - 1) ? 1u : 0u;
        }
        sC[0] = isLast;                // reuse LDS as broadcast
    }
    __syncthreads();

    // Last block: reduce the 256 partials and write the scalar.
    if (sC[0]) {
        float        L = 0.0f;
        unsigned int C = 0u;
        for (int i = t; i < NBLK; i += 256) {
            L += __hip_atomic_load(&pl[i], __ATOMIC_RELAXED,
                                   __HIP_MEMORY_SCOPE_AGENT);
            C += __hip_atomic_load(&pc[i], __ATOMIC_RELAXED,
                                   __HIP_MEMORY_SCOPE_AGENT);
        }
        for (int o = 32; o > 0; o >>= 1) {
            L += __shfl_down(L, o);
            C += __shfl_down(C, o);
        }
        __syncthreads();               // LDS reuse barrier
        if ((t & 63) == 0) { sL[wave] = L; sC[wave] = C; }
        __syncthreads();
        if (t == 0) {
            L = sL[0] + sL[1] + sL[2] + sL[3];
            C = sC[0] + sC[1] + sC[2] + sC[3];
            out[0] = L / (float)(1u + C);
        }
    }
}

extern "C" void kernel_launch(void* const* d_in, const int* in_sizes, int n_in,
                              void* d_out, int out_size, void* d_ws, size_t ws_size,
                              hipStream_t stream) {
    const float* x   = (const float*)d_in[0];   // inputs (8,19,512,512) f32
    const float* tgt = (const float*)d_in[1];   // targets (8,2048,20) f32
    const int*   sp  = (const int*)d_in[2];     // superpixels (8,512,512) i32
    const void*  spm = d_in[3];                 // spmasks (8,512,512), width detected

    unsigned int* flag = (unsigned int*)d_ws;
    unsigned int* st   = (unsigned int*)((char*)d_ws + 4);
    unsigned int* gt   = (unsigned int*)((char*)d_ws + 64);
    float*        pl   = (float*)((char*)d_ws + 1088);
    unsigned int* pc   = (unsigned int*)((char*)d_ws + 3136);
    unsigned int* bmt  = (unsigned int*)((char*)d_ws + 5184);

    prep<<<NROWS / 256, 256, 0, stream>>>(tgt, (const unsigned int*)spm,
                                          flag, st, gt, bmt);

    mcce_main<<<NBLK, 256, 0, stream>>>(x, sp, spm, bmt, flag,
                                        pl, pc, st, gt, (float*)d_out);
}

// Round 10
// 231.721 us; speedup vs baseline: 1.2308x; 1.0454x over previous
//
#include <hip/hip_runtime.h>

#define HW_   (512 * 512)   // pixels per image
#define NIMG  8
#define NC    19            // classes
#define NSP   2048          // superpixels per image
#define TC    20            // target row stride (C+1, last col sliced off)
#define NROWS (NIMG * NSP)  // 16384 target rows
#define TILE  1024          // pixels per tile (4 per thread)
#define NBLK  256           // persistent blocks: ONE per CU
#define NGRP  16            // completion-ticket groups (16 blocks each)
#define GSIZE (NBLK / NGRP)

typedef float vf4 __attribute__((ext_vector_type(4)));
typedef int   vi4 __attribute__((ext_vector_type(4)));

// d_ws layout:
//   [0]    flag (uint)       spmask width: 1 -> 4-byte, 0 -> 1-byte
//   [4]    st   (uint)       super ticket
//   [64]   gt[NGRP] uints, stride 16 (64 B apart -> no same-line RMWs)
//   [1088] pl[NBLK] float    per-block loss partials (contention-free)
//   [3136] pc[NBLK] uint     per-block count partials
//   [5184] bmt[NROWS] uint   per-(image,superpixel) multi-hot bitmask

// ---------------------------------------------------------------------------
// Kernel 1: zero tickets, detect spmask width, build target bitmasks.
// ---------------------------------------------------------------------------
__global__ __launch_bounds__(256) void prep(
    const float* __restrict__ tgt,
    const unsigned int* __restrict__ spm,
    unsigned int* __restrict__ flag, unsigned int* __restrict__ st,
    unsigned int* __restrict__ gt, unsigned int* __restrict__ bm) {

    int gid = blockIdx.x * 256 + threadIdx.x;   // 64 blocks -> 16384 threads
    if (gid == 0) *st = 0u;
    if (gid < NGRP) gt[gid * 16] = 0u;

    if (blockIdx.x == 1 && threadIdx.x < 64) {  // one wave: width detection
        unsigned int nonlow = 0, upper = 0;
        for (int i = threadIdx.x; i < 1024; i += 64) {
            unsigned int v = spm[i];
            nonlow |= (v & 0xFEFEFEFEu);
            upper  |= (v & 0xFFFFFF00u);
        }
        unsigned long long b1 = __ballot(nonlow != 0);
        unsigned long long b2 = __ballot(upper != 0);
        if (threadIdx.x == 0)
            *flag = ((b1 == 0ull) && (b2 != 0ull)) ? 0u : 1u;
    }

    const float* row = tgt + (size_t)gid * TC;  // one thread per target row
    unsigned int m = 0;
#pragma unroll
    for (int c = 0; c < NC; ++c)
        m |= (row[c] != 0.0f ? 1u : 0u) << c;
    bm[gid] = m;
}

// ---------------------------------------------------------------------------
// Kernel 2: R8 structure (1 block/CU, image-serial, nt burst) + cross-
// iteration prefetch, HAZARD-HARDENED:
//   - FULLY UNROLLED 8 iterations (no loop back-edge), distinct LAST-body
//     macro (no conditional between ISSUE and the tied wait), and the whole
//     pipelined region duplicated under the uniform flagv branch (prologue
//     ISSUE inside each arm) -> every in-flight asm-load destination is
//     SINGLE-ASSIGNMENT STRAIGHT-LINE code. No phis over in-flight regs =>
//     no compiler v_mov copies of not-yet-landed registers (R9's bug).
//   - vmcnt ledger per body: entry 20 (CUR burst) -> vmcnt(19) frees s4 ->
//     +4 gathers +1 mask = 24 -> +20 NXT burst = 44 -> vmcnt(20) drains
//     exactly CUR x19 + gathers + mask, NXT stays in flight. Last body:
//     no ISSUE, vmcnt(0). No compiler vmem exists in the region (all loop
//     vmem is asm; flagv load+wait resolve before the branch), so the
//     counts cannot be perturbed.
//   - FP order per pixel identical to R8 (ascending classes).
// ---------------------------------------------------------------------------
__global__ __launch_bounds__(256, 1) void mcce_main(
    const float* __restrict__ x,      // (N, C, H*W)
    const int*   __restrict__ sp,     // (N, H*W)
    const void*  __restrict__ spm,    // (N, H*W) mask, 1B or 4B elements
    const unsigned int* __restrict__ bmt,   // (N*NSP) bitmasks
    const unsigned int* __restrict__ flag,
    float* __restrict__ pl, unsigned int* __restrict__ pc,
    unsigned int* __restrict__ st, unsigned int* __restrict__ gt,
    float* __restrict__ out) {

    __shared__ float sL[4];
    __shared__ unsigned int sC[4];

    int b    = blockIdx.x;
    int t    = threadIdx.x;
    int wave = t >> 6;
    unsigned int flagv = *flag;        // compiler load+wait BEFORE the branch

    int tpb = (b & 255) * TILE;        // tile base pixel (constant per block)
    size_t thr4 = (size_t)tpb + 4 * t; // this thread's pixel offset in image

    vf4 A[NC], B[NC];
    vi4 s4A, s4B;
    float lsum = 0.0f;
    unsigned int lcnt = 0;

// Issue s4 + 19 nt x-loads for image N_ into (S4, D). No wait.
#define ISSUE(S4, D, N_) do {                                                  \
    const float* xb_  = x  + (size_t)(N_) * NC * HW_ + tpb;                    \
    const int*   spb_ = sp + (size_t)(N_) * HW_ + tpb;                         \
    unsigned int vo_  = (unsigned int)(t * 16);                                \
    asm volatile(                                                              \
        "global_load_dwordx4 %[s4],  %[vo], %[spb]\n\t"                        \
        "global_load_dwordx4 %[d0],  %[vo], %[xb] nt\n\t"                      \
        "v_add_u32 %[vo], 0x100000, %[vo]\n\t"                                 \
        "global_load_dwordx4 %[d1],  %[vo], %[xb] nt\n\t"                      \
        "v_add_u32 %[vo], 0x100000, %[vo]\n\t"                                 \
        "global_load_dwordx4 %[d2],  %[vo], %[xb] nt\n\t"                      \
        "v_add_u32 %[vo], 0x100000, %[vo]\n\t"                                 \
        "global_load_dwordx4 %[d3],  %[vo], %[xb] nt\n\t"                      \
        "v_add_u32 %[vo], 0x100000, %[vo]\n\t"                                 \
        "global_load_dwordx4 %[d4],  %[vo], %[xb] nt\n\t"                      \
        "v_add_u32 %[vo], 0x100000, %[vo]\n\t"                                 \
        "global_load_dwordx4 %[d5],  %[vo], %[xb] nt\n\t"                      \
        "v_add_u32 %[vo], 0x100000, %[vo]\n\t"                                 \
        "global_load_dwordx4 %[d6],  %[vo], %[xb] nt\n\t"                      \
        "v_add_u32 %[vo], 0x100000, %[vo]\n\t"                                 \
        "global_load_dwordx4 %[d7],  %[vo], %[xb] nt\n\t"                      \
        "v_add_u32 %[vo], 0x100000, %[vo]\n\t"                                 \
        "global_load_dwordx4 %[d8],  %[vo], %[xb] nt\n\t"                      \
        "v_add_u32 %[vo], 0x100000, %[vo]\n\t"                                 \
        "global_load_dwordx4 %[d9],  %[vo], %[xb] nt\n\t"                      \
        "v_add_u32 %[vo], 0x100000, %[vo]\n\t"                                 \
        "global_load_dwordx4 %[d10], %[vo], %[xb] nt\n\t"                      \
        "v_add_u32 %[vo], 0x100000, %[vo]\n\t"                                 \
        "global_load_dwordx4 %[d11], %[vo], %[xb] nt\n\t"                      \
        "v_add_u32 %[vo], 0x100000, %[vo]\n\t"                                 \
        "global_load_dwordx4 %[d12], %[vo], %[xb] nt\n\t"                      \
        "v_add_u32 %[vo], 0x100000, %[vo]\n\t"                                 \
        "global_load_dwordx4 %[d13], %[vo], %[xb] nt\n\t"                      \
        "v_add_u32 %[vo], 0x100000, %[vo]\n\t"                                 \
        "global_load_dwordx4 %[d14], %[vo], %[xb] nt\n\t"                      \
        "v_add_u32 %[vo], 0x100000, %[vo]\n\t"                                 \
        "global_load_dwordx4 %[d15], %[vo], %[xb] nt\n\t"                      \
        "v_add_u32 %[vo], 0x100000, %[vo]\n\t"                                 \
        "global_load_dwordx4 %[d16], %[vo], %[xb] nt\n\t"                      \
        "v_add_u32 %[vo], 0x100000, %[vo]\n\t"                                 \
        "global_load_dwordx4 %[d17], %[vo], %[xb] nt\n\t"                      \
        "v_add_u32 %[vo], 0x100000, %[vo]\n\t"                                 \
        "global_load_dwordx4 %[d18], %[vo], %[xb] nt"                          \
        : [d0]"=v"(D[0]),  [d1]"=v"(D[1]),  [d2]"=v"(D[2]),  [d3]"=v"(D[3]),   \
          [d4]"=v"(D[4]),  [d5]"=v"(D[5]),  [d6]"=v"(D[6]),  [d7]"=v"(D[7]),   \
          [d8]"=v"(D[8]),  [d9]"=v"(D[9]),  [d10]"=v"(D[10]),[d11]"=v"(D[11]), \
          [d12]"=v"(D[12]),[d13]"=v"(D[13]),[d14]"=v"(D[14]),[d15]"=v"(D[15]), \
          [d16]"=v"(D[16]),[d17]"=v"(D[17]),[d18]"=v"(D[18]),                  \
          [s4]"=v"(S4), [vo]"+v"(vo_)                                          \
        : [xb]"s"(xb_), [spb]"s"(spb_));                                       \
} while (0)

#define TIES(D) "+v"(D[0]), "+v"(D[1]), "+v"(D[2]), "+v"(D[3]), "+v"(D[4]),    \
                "+v"(D[5]), "+v"(D[6]), "+v"(D[7]), "+v"(D[8]), "+v"(D[9]),    \
                "+v"(D[10]), "+v"(D[11]), "+v"(D[12]), "+v"(D[13]),            \
                "+v"(D[14]), "+v"(D[15]), "+v"(D[16]), "+v"(D[17]), "+v"(D[18])

// Gathers for body IT (addresses from CS4, just retired by vmcnt(19)).
#define GATH(CS4, IT) \
    asm volatile("s_waitcnt vmcnt(19)" : "+v"(CS4));                           \
    __builtin_amdgcn_sched_barrier(0);                                         \
    const unsigned int* bt_ = bmt + (IT) * NSP;                                \
    const unsigned int* a0_ = bt_ + CS4.x;                                     \
    const unsigned int* a1_ = bt_ + CS4.y;                                     \
    const unsigned int* a2_ = bt_ + CS4.z;                                     \
    const unsigned int* a3_ = bt_ + CS4.w;                                     \
    unsigned int g0_, g1_, g2_, g3_;                                           \
    asm volatile("global_load_dword %0, %4, off\n\t"                           \
                 "global_load_dword %1, %5, off\n\t"                           \
                 "global_load_dword %2, %6, off\n\t"                           \
                 "global_load_dword %3, %7, off"                               \
        : "=&v"(g0_), "=&v"(g1_), "=&v"(g2_), "=&v"(g3_)                       \
        : "v"(a0_), "v"(a1_), "v"(a2_), "v"(a3_));

// Shared compute tail (after the data-ready wait).
#define COMP(CD) \
    float se0=0, se1=0, se2=0, se3=0, ts0=0, ts1=0, ts2=0, ts3=0;              \
    _Pragma("unroll")                                                          \
    for (int c = 0; c < NC; ++c) {                                             \
        float e0 = __expf(CD[c].x), e1 = __expf(CD[c].y);                      \
        float e2 = __expf(CD[c].z), e3 = __expf(CD[c].w);                      \
        se0 += e0; se1 += e1; se2 += e2; se3 += e3;                            \
        ts0 += ((g0_ >> c) & 1) ? e0 : 0.0f;                                   \
        ts1 += ((g1_ >> c) & 1) ? e1 : 0.0f;                                   \
        ts2 += ((g2_ >> c) & 1) ? e2 : 0.0f;                                   \
        ts3 += ((g3_ >> c) & 1) ? e3 : 0.0f;                                   \
    }                                                                          \
    if ((mk0 != 0) && (g0_ != 0u)) { lsum -= __logf(ts0/se0 + 1e-8f); ++lcnt; }\
    if ((mk1 != 0) && (g1_ != 0u)) { lsum -= __logf(ts1/se1 + 1e-8f); ++lcnt; }\
    if ((mk2 != 0) && (g2_ != 0u)) { lsum -= __logf(ts2/se2 + 1e-8f); ++lcnt; }\
    if ((mk3 != 0) && (g3_ != 0u)) { lsum -= __logf(ts3/se3 + 1e-8f); ++lcnt; }

// 4-byte-mask bodies (steady-state / last).
#define BODY4(CS4, CD, NS4, ND, IT) do {                                       \
    GATH(CS4, IT)                                                              \
    vi4 m4_;                                                                   \
    const vi4* pm_ = (const vi4*)((const int*)spm + (size_t)(IT) * HW_ + thr4);\
    asm volatile("global_load_dwordx4 %0, %1, off" : "=&v"(m4_) : "v"(pm_));   \
    ISSUE(NS4, ND, (IT) + 1);                                                  \
    asm volatile("s_waitcnt vmcnt(20)"                                         \
        : TIES(CD), "+v"(g0_), "+v"(g1_), "+v"(g2_), "+v"(g3_), "+v"(m4_));    \
    __builtin_amdgcn_sched_barrier(0);                                         \
    int mk0 = m4_.x, mk1 = m4_.y, mk2 = m4_.z, mk3 = m4_.w;                    \
    COMP(CD)                                                                   \
} while (0)

#define BODY4L(CS4, CD, IT) do {                                               \
    GATH(CS4, IT)                                                              \
    vi4 m4_;                                                                   \
    const vi4* pm_ = (const vi4*)((const int*)spm + (size_t)(IT) * HW_ + thr4);\
    asm volatile("global_load_dwordx4 %0, %1, off" : "=&v"(m4_) : "v"(pm_));   \
    asm volatile("s_waitcnt vmcnt(0)"                                          \
        : TIES(CD), "+v"(g0_), "+v"(g1_), "+v"(g2_), "+v"(g3_), "+v"(m4_));    \
    __builtin_amdgcn_sched_barrier(0);                                         \
    int mk0 = m4_.x, mk1 = m4_.y, mk2 = m4_.z, mk3 = m4_.w;                    \
    COMP(CD)                                                                   \
} while (0)

// 1-byte-mask bodies.
#define BODY1(CS4, CD, NS4, ND, IT) do {                                       \
    GATH(CS4, IT)                                                              \
    unsigned int mw_;                                                          \
    const unsigned int* pm_ = (const unsigned int*)                            \
        ((const unsigned char*)spm + (size_t)(IT) * HW_ + thr4);               \
    asm volatile("global_load_dword %0, %1, off" : "=&v"(mw_) : "v"(pm_));     \
    ISSUE(NS4, ND, (IT) + 1);                                                  \
    asm volatile("s_waitcnt vmcnt(20)"                                         \
        : TIES(CD), "+v"(g0_), "+v"(g1_), "+v"(g2_), "+v"(g3_), "+v"(mw_));    \
    __builtin_amdgcn_sched_barrier(0);                                         \
    int mk0 = mw_ & 0xFF, mk1 = (mw_ >> 8) & 0xFF;                             \
    int mk2 = (mw_ >> 16) & 0xFF, mk3 = (mw_ >> 24) & 0xFF;                    \
    COMP(CD)                                                                   \
} while (0)

#define BODY1L(CS4, CD, IT) do {                                               \
    GATH(CS4, IT)                                                              \
    unsigned int mw_;                                                          \
    const unsigned int* pm_ = (const unsigned int*)                            \
        ((const unsigned char*)spm + (size_t)(IT) * HW_ + thr4);               \
    asm volatile("global_load_dword %0, %1, off" : "=&v"(mw_) : "v"(pm_));     \
    asm volatile("s_waitcnt vmcnt(0)"                                          \
        : TIES(CD), "+v"(g0_), "+v"(g1_), "+v"(g2_), "+v"(g3_), "+v"(mw_));    \
    __builtin_amdgcn_sched_barrier(0);                                         \
    int mk0 = mw_ & 0xFF, mk1 = (mw_ >> 8) & 0xFF;                             \
    int mk2 = (mw_ >> 16) & 0xFF, mk3 = (mw_ >> 24) & 0xFF;                    \
    COMP(CD)                                                                   \
} while (0)

    if (flagv) {
        ISSUE(s4A, A, 0);              // prologue inside the arm: nothing of
        BODY4(s4A, A, s4B, B, 0);      // ours in flight at the branch point
        BODY4(s4B, B, s4A, A, 1);
        BODY4(s4A, A, s4B, B, 2);
        BODY4(s4B, B, s4A, A, 3);
        BODY4(s4A, A, s4B, B, 4);
        BODY4(s4B, B, s4A, A, 5);
        BODY4(s4A, A, s4B, B, 6);
        BODY4L(s4B, B, 7);
    } else {
        ISSUE(s4A, A, 0);
        BODY1(s4A, A, s4B, B, 0);
        BODY1(s4B, B, s4A, A, 1);
        BODY1(s4A, A, s4B, B, 2);
        BODY1(s4B, B, s4A, A, 3);
        BODY1(s4A, A, s4B, B, 4);
        BODY1(s4B, B, s4A, A, 5);
        BODY1(s4A, A, s4B, B, 6);
        BODY1L(s4B, B, 7);
    }

#undef BODY1L
#undef BODY1
#undef BODY4L
#undef BODY4
#undef COMP
#undef GATH
#undef TIES
#undef ISSUE

    // Wave-64 shuffle reduction -> LDS block reduction.
    for (int o = 32; o > 0; o >>= 1) {
        lsum += __shfl_down(lsum, o);
        lcnt += __shfl_down(lcnt, o);
    }
    if ((t & 63) == 0) { sL[wave] = lsum; sC[wave] = lcnt; }
    __syncthreads();

    if (t == 0) {
        float        L = sL[0] + sL[1] + sL[2] + sL[3];
        unsigned int C = sC[0] + sC[1] + sC[2] + sC[3];
        __hip_atomic_store(&pl[b], L, __ATOMIC_RELAXED,
                           __HIP_MEMORY_SCOPE_AGENT);
        __hip_atomic_store(&pc[b], C, __ATOMIC_RELAXED,
                           __HIP_MEMORY_SCOPE_AGENT);
        // Hierarchical tickets: 16 groups of 16 (64-B-padded lines), then
        // one super ticket -> max ~16 same-line RMWs anywhere.
        unsigned int g = (unsigned int)b / GSIZE;
        unsigned int isLast = 0u;
        unsigned int tk = __hip_atomic_fetch_add(&gt[g * 16], 1u,
                              __ATOMIC_ACQ_REL, __HIP_MEMORY_SCOPE_AGENT);
        if (tk == (unsigned int)(GSIZE - 1)) {
            unsigned int s = __hip_atomic_fetch_add(st, 1u,
                                 __ATOMIC_ACQ_REL, __HIP_MEMORY_SCOPE_AGENT);
            isLast = (s == NGRP - 1) ? 1u : 0u;
        }
        sC[0] = isLast;                // reuse LDS as broadcast
    }
    __syncthreads();

    // Last block: reduce the 256 partials and write the scalar.
    if (sC[0]) {
        float        L = 0.0f;
        unsigned int C = 0u;
        for (int i = t; i < NBLK; i += 256) {
            L += __hip_atomic_load(&pl[i], __ATOMIC_RELAXED,
                                   __HIP_MEMORY_SCOPE_AGENT);
            C += __hip_atomic_load(&pc[i], __ATOMIC_RELAXED,
                                   __HIP_MEMORY_SCOPE_AGENT);
        }
        for (int o = 32; o > 0; o >>= 1) {
            L += __shfl_down(L, o);
            C += __shfl_down(C, o);
        }
        __syncthreads();               // LDS reuse barrier
        if ((t & 63) == 0) { sL[wave] = L; sC[wave] = C; }
        __syncthreads();
        if (t == 0) {
            L = sL[0] + sL[1] + sL[2] + sL[3];
            C = sC[0] + sC[1] + sC[2] + sC[3];
            out[0] = L / (float)(1u + C);
        }
    }
}

extern "C" void kernel_launch(void* const* d_in, const int* in_sizes, int n_in,
                              void* d_out, int out_size, void* d_ws, size_t ws_size,
                              hipStream_t stream) {
    const float* x   = (const float*)d_in[0];   // inputs (8,19,512,512) f32
    const float* tgt = (const float*)d_in[1];   // targets (8,2048,20) f32
    const int*   sp  = (const int*)d_in[2];     // superpixels (8,512,512) i32
    const void*  spm = d_in[3];                 // spmasks (8,512,512), width detected

    unsigned int* flag = (unsigned int*)d_ws;
    unsigned int* st   = (unsigned int*)((char*)d_ws + 4);
    unsigned int* gt   = (unsigned int*)((char*)d_ws + 64);
    float*        pl   = (float*)((char*)d_ws + 1088);
    unsigned int* pc   = (unsigned int*)((char*)d_ws + 3136);
    unsigned int* bmt  = (unsigned int*)((char*)d_ws + 5184);

    prep<<<NROWS / 256, 256, 0, stream>>>(tgt, (const unsigned int*)spm,
                                          flag, st, gt, bmt);

    mcce_main<<<NBLK, 256, 0, stream>>>(x, sp, spm, bmt, flag,
                                        pl, pc, st, gt, (float*)d_out);
}